// Round 8
// baseline (1117.763 us; speedup 1.0000x reference)
//
#include <hip/hip_runtime.h>

typedef short bf16x8 __attribute__((ext_vector_type(8)));
typedef float f32x4 __attribute__((ext_vector_type(4)));

#define S_LEN 2048
#define NHQ 16
#define NKV 8
#define HD 256
#define QKV_STR 8192   // packed QKV row stride (shorts): [q 4096 | k 2048 | v 2048]
#define KOFF 4096
#define VOFF 6144

__device__ __forceinline__ unsigned short f2bf(float f){
  unsigned u = __float_as_uint(f);
  unsigned r = (u + 0x7FFFu + ((u >> 16) & 1u)) >> 16;
  return (unsigned short)r;
}
__device__ __forceinline__ float bf2f(unsigned short h){
  return __uint_as_float(((unsigned)h) << 16);
}
__device__ __forceinline__ unsigned pack2(float a, float b){
  return (unsigned)f2bf(a) | ((unsigned)f2bf(b) << 16);
}

// async global->LDS, 16B per lane; LDS dest is wave-uniform base + lane*16 (HW-linear)
__device__ __forceinline__ void gload_lds16(const void* g, void* l){
  __builtin_amdgcn_global_load_lds(
      (const __attribute__((address_space(1))) void*)g,
      (__attribute__((address_space(3))) void*)l, 16, 0, 0);
}

// ---------------- elementwise f32 -> bf16 ----------------
__global__ void k_conv(const float* __restrict__ in, unsigned short* __restrict__ out, int n){
  int i = (blockIdx.x * 256 + threadIdx.x) * 4;
  if (i < n){
    float4 v = *(const float4*)&in[i];
    ushort4 o;
    o.x = f2bf(v.x); o.y = f2bf(v.y); o.z = f2bf(v.z); o.w = f2bf(v.w);
    *(ushort4*)&out[i] = o;
  }
}

// ---------------- tiled transpose + convert: in (R x C) f32 -> out (C x R) bf16 ----------------
__global__ void k_tconv(const float* __restrict__ in, unsigned short* __restrict__ out, int R, int C){
  __shared__ float tile[32][33];
  int c0 = blockIdx.x * 32, r0 = blockIdx.y * 32;
  int tx = threadIdx.x, ty = threadIdx.y;
  for (int i = 0; i < 4; i++)
    tile[ty + i*8][tx] = in[(size_t)(r0 + ty + i*8) * C + c0 + tx];
  __syncthreads();
  for (int i = 0; i < 4; i++)
    out[(size_t)(c0 + ty + i*8) * R + r0 + tx] = f2bf(tile[tx][ty + i*8]);
}

// ---------------- bf16 transpose for V: per (b,kv): packed QKV (S x 8192) -> VT (D x S) ----
__global__ void k_vtrans(const unsigned short* __restrict__ Vsrc, unsigned short* __restrict__ VT){
  __shared__ unsigned short tile[32][40];
  int s0 = blockIdx.x * 32, d0 = blockIdx.y * 32, bz = blockIdx.z; // bz = b*NKV+kv
  int b = bz >> 3, kv = bz & 7;
  int tx = threadIdx.x, ty = threadIdx.y;
  for (int i = 0; i < 4; i++)
    tile[ty + i*8][tx] = Vsrc[(size_t)(b * S_LEN + s0 + ty + i*8) * QKV_STR + VOFF + kv*HD + d0 + tx];
  __syncthreads();
  for (int i = 0; i < 4; i++)
    VT[((size_t)(bz * HD + d0 + ty + i*8)) * S_LEN + s0 + tx] = tile[tx][ty + i*8];
}

// ---------------- in-place RoPE on packed bf16 buffer, vectorized x8 ----------------
__global__ void k_rope(unsigned short* buf, const float* __restrict__ cosb,
                       const float* __restrict__ sinb, int lgnh, int stride, int coff){
  int idx = blockIdx.x * 256 + threadIdx.x;
  int d0 = (idx & 15) * 8;
  int h = (idx >> 4) & ((1 << lgnh) - 1);
  int t = idx >> (4 + lgnh);
  float ca[8], sa[8];
  *(float4*)&ca[0] = *(const float4*)&cosb[t * 128 + d0];
  *(float4*)&ca[4] = *(const float4*)&cosb[t * 128 + d0 + 4];
  *(float4*)&sa[0] = *(const float4*)&sinb[t * 128 + d0];
  *(float4*)&sa[4] = *(const float4*)&sinb[t * 128 + d0 + 4];
  size_t base = (size_t)t * stride + coff + ((size_t)h << 8) + d0;
  bf16x8 x1 = *(const bf16x8*)&buf[base];
  bf16x8 x2 = *(const bf16x8*)&buf[base + 128];
  bf16x8 o1, o2;
  #pragma unroll
  for (int j = 0; j < 8; j++){
    float f1 = bf2f((unsigned short)x1[j]), f2 = bf2f((unsigned short)x2[j]);
    o1[j] = (short)f2bf(f1 * ca[j] - f2 * sa[j]);
    o2[j] = (short)f2bf(f1 * sa[j] + f2 * ca[j]);
  }
  *(bf16x8*)&buf[base] = o1;
  *(bf16x8*)&buf[base + 128] = o2;
}

// ---------------- bf16 GEMM: C(MxN) = A(MxK) @ Bt(NxK)^T ; out f32 or bf16 ----------------
// staging via global_load_lds width=16 with linear LDS dest + inverse-XOR-swizzled global
// source; XCD-bijective block swizzle (T1).
__global__ __launch_bounds__(256) void k_gemm_bt(const unsigned short* __restrict__ A,
    const unsigned short* __restrict__ Bt, void* __restrict__ Cp,
    int M, int N, int K, int out_bf16){
  __shared__ __align__(16) unsigned short smem[2 * 128 * 64];  // 32 KB: As|Bs, reused as C-stage
  unsigned short* As = smem;
  unsigned short* Bs = smem + 128 * 64;
  int tid = threadIdx.x;
  int lane = tid & 63, wave = tid >> 6, quad = lane >> 4, l16 = lane & 15;
  int wm = wave >> 1, wn = wave & 1;
  // XCD-bijective swizzle: all launches have nwg % 8 == 0
  int nx = gridDim.x;
  int flat = blockIdx.y * nx + blockIdx.x;
  int cpx = (nx * gridDim.y) >> 3;
  int swz = (flat & 7) * cpx + (flat >> 3);
  int bm0 = (swz / nx) * 128, bn0 = (swz % nx) * 128;
  const unsigned short* Ag = &A[(size_t)bm0 * K];
  const unsigned short* Bg = &Bt[(size_t)bn0 * K];
  int srow = lane >> 3;                 // row-in-window
  int spc  = lane & 7;                  // LDS chunk index (linear dest)
  f32x4 acc[4][4] = {};
  for (int k0 = 0; k0 < K; k0 += 64){
    __syncthreads();
    // async staging: 16 windows x 1KB per matrix; window = it*4 + wave (wave-uniform dest)
    for (int it = 0; it < 4; it++){
      int win = it * 4 + wave;
      int row = win * 8 + srow;
      int c   = spc ^ (row & 7);        // inverse swizzle on SOURCE; LDS stays linear
      gload_lds16(&Ag[(size_t)row * K + k0 + c * 8], &As[win * 512]);
      gload_lds16(&Bg[(size_t)row * K + k0 + c * 8], &Bs[win * 512]);
    }
    __syncthreads();                    // compiler drains vmcnt(0) before barrier
    for (int ks = 0; ks < 2; ks++){
      bf16x8 af[4], bfr[4];
      for (int mt = 0; mt < 4; mt++){
        int row = wm * 64 + mt * 16 + l16;
        int pc = (ks * 4 + quad) ^ (row & 7);
        af[mt] = *(const bf16x8*)&As[row * 64 + pc * 8];
      }
      for (int nt = 0; nt < 4; nt++){
        int row = wn * 64 + nt * 16 + l16;
        int pc = (ks * 4 + quad) ^ (row & 7);
        bfr[nt] = *(const bf16x8*)&Bs[row * 64 + pc * 8];
      }
      for (int mt = 0; mt < 4; mt++)
        for (int nt = 0; nt < 4; nt++)
          acc[mt][nt] = __builtin_amdgcn_mfma_f32_16x16x32_bf16(af[mt], bfr[nt], acc[mt][nt], 0, 0, 0);
    }
  }
  // ---- coalesced epilogue: stage 64 rows of C at a time in LDS, store 16B/lane ----
  float* Ct = (float*)smem;  // 64 x 128 f32 = 32 KB
  for (int p = 0; p < 2; p++){
    __syncthreads();
    if (wm == p){
      for (int mt = 0; mt < 4; mt++)
        for (int nt = 0; nt < 4; nt++)
          for (int r = 0; r < 4; r++)
            Ct[(mt * 16 + quad * 4 + r) * 128 + wn * 64 + nt * 16 + l16] = acc[mt][nt][r];
    }
    __syncthreads();
    if (out_bf16){
      unsigned short* O = (unsigned short*)Cp;
      for (int j = 0; j < 4; j++){
        int chunk = j * 256 + tid;        // 1024 chunks x 8 elems
        int row = chunk >> 4, col = (chunk & 15) * 8;
        const float* src = &Ct[row * 128 + col];
        uint4 o;
        o.x = pack2(src[0], src[1]);
        o.y = pack2(src[2], src[3]);
        o.z = pack2(src[4], src[5]);
        o.w = pack2(src[6], src[7]);
        *(uint4*)&O[(size_t)(bm0 + p * 64 + row) * N + bn0 + col] = o;
      }
    } else {
      float* O = (float*)Cp;
      for (int j = 0; j < 8; j++){
        int chunk = j * 256 + tid;        // 2048 chunks x 4 elems
        int row = chunk >> 5, col = (chunk & 31) * 4;
        *(float4*)&O[(size_t)(bm0 + p * 64 + row) * N + bn0 + col] = *(const float4*)&Ct[row * 128 + col];
      }
    }
  }
}

// ---------------- flash attention (v9: v4 dbuf structure + conflict-free swizzled LDS) ------
// Q,K read from packed QKV buffer (token, 8192): q at 0, k at 4096. VT (b,kv,256,S) bf16.
// Out (token, 16*256) bf16.
// grid (x=bkv=16, y=p=16), block 512 = 8 waves: wave = rowgrp(4) x head-in-group(2).
// linear id = p*16+bkv -> id%8 == bkv%8: XCD-local K/VT (v4-verified FETCH 265->33 MB).
// Block p runs q-tiles {p, 31-p}: exactly 66 k-tiles per block.
// v4-proven schedule: dbuf, reg-prefetch of tile kt+1, ONE barrier per k-tile.
// v7/v8-proven conflict-free LDS (2.67e7 -> ~4e6): Ks stride 256 + 16B-chunk XOR
// involution (write (c^kr), read (chunk^row)); VTs stride 36 shorts (18 dwords).
__global__ __launch_bounds__(512, 2) void k_flash(const unsigned short* __restrict__ QKV,
    const unsigned short* __restrict__ VTg, unsigned short* __restrict__ Og){
  // [buf0: Ks 32x256 swz (8192) | VTs 256x36 (9216)][buf1: same][Ps 8x16x40 (5120)]
  // = 39936 shorts = 78 KB; epilogue reuses as 8 waves x 16x256 = 32768 shorts.
  __shared__ __align__(16) unsigned short smem[2 * 17408 + 8 * 16 * 40];
  const int BUFSZ = 17408;
  int tid = threadIdx.x;
  int lane = tid & 63, wave = tid >> 6, quad = lane >> 4, l16 = lane & 15;
  int hig = wave & 1, rowgrp = wave >> 1;        // 2 heads share this block's K/V staging
  int bkv = blockIdx.x, p = blockIdx.y;
  int b = bkv >> 3, kv = bkv & 7;
  int h = kv * 2 + hig;
  const float L2E = 1.4426950408889634f;
  const float scale = 0.0625f; // 1/sqrt(256)

  size_t kgbase = (size_t)(b * S_LEN) * QKV_STR + KOFF + (size_t)kv * HD;
  size_t vtbase = ((size_t)(b * NKV + kv) * HD) * S_LEN;
  unsigned short* Ps = smem + 2 * BUFSZ + wave * (16 * 40);

  for (int ph = 0; ph < 2; ph++){
    int qt = ph ? (31 - p) : p;
    int qmin = qt * 64 + rowgrp * 16;
    int nkt = qt * 2 + 2;

    // Q fragments in registers: this wave's 16 q-rows for head h
    bf16x8 qf[8];
    {
      size_t qoff = ((size_t)(b * S_LEN + qt * 64 + rowgrp * 16 + l16)) * QKV_STR + (size_t)h * HD;
      for (int ks = 0; ks < 8; ks++)
        qf[ks] = *(const bf16x8*)&QKV[qoff + ks * 32 + quad * 8];
    }
    f32x4 acc[16] = {};
    float mrow[4], lrow[4];
    for (int r = 0; r < 4; r++){ mrow[r] = -1e30f; lrow[r] = 0.f; }

    // prologue: prefetch tile 0 into registers
    uint4 stk[2], stv[2];
    for (int it = 0; it < 2; it++){
      int slot = it * 512 + tid;
      int kr = slot >> 5, c = slot & 31;
      stk[it] = *(const uint4*)&QKV[kgbase + (size_t)kr * QKV_STR + c * 8];
      int dd = slot >> 2, c2 = slot & 3;
      stv[it] = *(const uint4*)&VTg[vtbase + (size_t)dd * S_LEN + c2 * 8];
    }

    for (int kt = 0; kt < nkt; kt++){
      unsigned short* Ks  = smem + (kt & 1) * BUFSZ;
      unsigned short* VTs = Ks + 8192;
      // write staged regs (tile kt) -> LDS buf[kt&1], swizzled
      for (int it = 0; it < 2; it++){
        int slot = it * 512 + tid;
        int kr = slot >> 5, c = slot & 31;
        *(uint4*)&Ks[kr * 256 + (c ^ kr) * 8] = stk[it];
        int dd = slot >> 2, c2 = slot & 3;
        *(uint4*)&VTs[dd * 36 + c2 * 8] = stv[it];
      }
      // prefetch tile kt+1 -> registers (latency hides under barrier+compute)
      if (kt + 1 < nkt){
        for (int it = 0; it < 2; it++){
          int slot = it * 512 + tid;
          int kr = slot >> 5, c = slot & 31;
          stk[it] = *(const uint4*)&QKV[kgbase + (size_t)((kt + 1) * 32 + kr) * QKV_STR + c * 8];
          int dd = slot >> 2, c2 = slot & 3;
          stv[it] = *(const uint4*)&VTg[vtbase + (size_t)dd * S_LEN + (kt + 1) * 32 + c2 * 8];
        }
      }
      __syncthreads();
      if (kt * 32 > qmin + 15) continue;  // wave-uniform: tile fully above causal diag

      // S = Q @ K^T  (16 x 32 per wave)
      f32x4 sv[2] = {};
      __builtin_amdgcn_s_setprio(1);
      for (int ks = 0; ks < 8; ks++){
        for (int nt = 0; nt < 2; nt++){
          int row = nt * 16 + l16;
          bf16x8 kf = *(const bf16x8*)&Ks[row * 256 + ((ks * 4 + quad) ^ row) * 8];
          sv[nt] = __builtin_amdgcn_mfma_f32_16x16x32_bf16(qf[ks], kf, sv[nt], 0, 0, 0);
        }
      }
      __builtin_amdgcn_s_setprio(0);
      // scale + causal mask + row max (rows = quad*4+r, cols = kt*32 + nt*16 + l16)
      float pv[2][4], tmax[4];
      for (int r = 0; r < 4; r++){
        int qr = qmin + quad * 4 + r;
        float mx = -1e30f;
        for (int nt = 0; nt < 2; nt++){
          int key = kt * 32 + nt * 16 + l16;
          float v = sv[nt][r] * scale;
          if (key > qr) v = -1e30f;
          pv[nt][r] = v;
          mx = fmaxf(mx, v);
        }
        tmax[r] = mx;
      }
      for (int off = 1; off < 16; off <<= 1)
        for (int r = 0; r < 4; r++)
          tmax[r] = fmaxf(tmax[r], __shfl_xor(tmax[r], off, 64));
      // defer-max THR=0: skip rescale when no row max grew (skipped work is exactly *1.0)
      int grow = (tmax[0] > mrow[0]) | (tmax[1] > mrow[1]) |
                 (tmax[2] > mrow[2]) | (tmax[3] > mrow[3]);
      if (grow){
        float alpha[4];
        for (int r = 0; r < 4; r++){
          float mn = fmaxf(mrow[r], tmax[r]);
          alpha[r] = exp2f((mrow[r] - mn) * L2E);
          mrow[r] = mn;
          lrow[r] *= alpha[r];
        }
        for (int i = 0; i < 16; i++)
          for (int r = 0; r < 4; r++) acc[i][r] *= alpha[r];
      }
      float pb[2][4], psum[4] = {0.f, 0.f, 0.f, 0.f};
      for (int nt = 0; nt < 2; nt++)
        for (int r = 0; r < 4; r++){
          float pe = exp2f((pv[nt][r] - mrow[r]) * L2E);
          pb[nt][r] = pe; psum[r] += pe;
        }
      for (int off = 1; off < 16; off <<= 1)
        for (int r = 0; r < 4; r++)
          psum[r] += __shfl_xor(psum[r], off, 64);
      for (int r = 0; r < 4; r++) lrow[r] += psum[r];
      // P: C-layout -> LDS -> A-layout (per-wave private, no barrier needed)
      for (int nt = 0; nt < 2; nt++)
        for (int r = 0; r < 4; r++)
          Ps[(quad * 4 + r) * 40 + nt * 16 + l16] = f2bf(pb[nt][r]);
      bf16x8 pa = *(const bf16x8*)&Ps[l16 * 40 + quad * 8];
      // O += P @ V   (16 x 256 per wave)
      __builtin_amdgcn_s_setprio(1);
      for (int nt = 0; nt < 16; nt++){
        bf16x8 vf = *(const bf16x8*)&VTs[(nt * 16 + l16) * 36 + quad * 8];
        acc[nt] = __builtin_amdgcn_mfma_f32_16x16x32_bf16(pa, vf, acc[nt], 0, 0, 0);
      }
      __builtin_amdgcn_s_setprio(0);
    }
    // ---- coalesced epilogue: per-wave O tile (16 x 256 bf16) via LDS, 16B/lane stores ----
    float inv[4];
    for (int r = 0; r < 4; r++) inv[r] = 1.0f / lrow[r];
    __syncthreads();  // all waves done with Ks/VTs
    unsigned short* Ot = smem + wave * (16 * 256);  // 8 KB per wave (fits in dbuf region)
    for (int nt = 0; nt < 16; nt++)
      for (int r = 0; r < 4; r++)
        Ot[(quad * 4 + r) * 256 + nt * 16 + l16] = f2bf(acc[nt][r] * inv[r]);
    size_t obase = ((size_t)(b * S_LEN + qt * 64 + rowgrp * 16)) * (NHQ * HD) + (size_t)h * HD;
    for (int j = 0; j < 8; j++){
      int chunk = j * 64 + lane;      // 512 chunks x 8 shorts
      int row = chunk >> 5, col = (chunk & 31) * 8;
      *(uint4*)&Og[obase + (size_t)row * (NHQ * HD) + col] = *(const uint4*)&Ot[row * 256 + col];
    }
    __syncthreads();  // epilogue reads done before next phase's staging overwrites
  }
}

extern "C" void kernel_launch(void* const* d_in, const int* in_sizes, int n_in,
                              void* d_out, int out_size, void* d_ws, size_t ws_size,
                              hipStream_t stream){
  const float* hid  = (const float*)d_in[0];
  const float* cosb = (const float*)d_in[1];
  const float* sinb = (const float*)d_in[2];
  // d_in[3] = mask (causal, reconstructed analytically)
  const float* wq = (const float*)d_in[4];
  const float* wk = (const float*)d_in[5];
  const float* wv = (const float*)d_in[6];
  const float* wo = (const float*)d_in[7];

  char* ws = (char*)d_ws;
  size_t off = 0;
  auto alloc = [&](size_t bytes) -> void* {
    void* p = ws + off; off += (bytes + 255) & ~(size_t)255; return p;
  };
  unsigned short* Xbf   = (unsigned short*)alloc(4096ull * 3072 * 2);
  unsigned short* WqkvT = (unsigned short*)alloc(8192ull * 3072 * 2);  // [wq|wk|wv] cols as rows
  unsigned short* WoT   = (unsigned short*)alloc(3072ull * 4096 * 2);
  unsigned short* QKVb  = (unsigned short*)alloc(4096ull * 8192 * 2);  // packed per-token q|k|v
  unsigned short* VTb   = (unsigned short*)alloc(4096ull * 2048 * 2);
  unsigned short* Ab    = (unsigned short*)alloc(4096ull * 4096 * 2);

  k_conv<<<12288, 256, 0, stream>>>(hid, Xbf, 4096 * 3072);
  k_tconv<<<dim3(128, 96), dim3(32, 8), 0, stream>>>(wq, WqkvT, 3072, 4096);
  k_tconv<<<dim3(64, 96),  dim3(32, 8), 0, stream>>>(wk, WqkvT + 4096ull * 3072, 3072, 2048);
  k_tconv<<<dim3(64, 96),  dim3(32, 8), 0, stream>>>(wv, WqkvT + 6144ull * 3072, 3072, 2048);
  k_tconv<<<dim3(96, 128), dim3(32, 8), 0, stream>>>(wo, WoT, 4096, 3072);
  // fused QKV projection: one N=8192 GEMM instead of {4096, 2048, 2048}
  k_gemm_bt<<<dim3(64, 32), 256, 0, stream>>>(Xbf, WqkvT, QKVb, 4096, 8192, 3072, 1);
  k_rope<<<4096, 256, 0, stream>>>(QKVb, cosb, sinb, 4, QKV_STR, 0);
  k_rope<<<2048, 256, 0, stream>>>(QKVb, cosb, sinb, 3, QKV_STR, KOFF);
  k_vtrans<<<dim3(64, 8, 16), dim3(32, 8), 0, stream>>>(QKVb, VTb);
  k_flash<<<dim3(16, 16), 512, 0, stream>>>(QKVb, VTb, Ab);
  k_gemm_bt<<<dim3(24, 32), 256, 0, stream>>>(Ab, WoT, d_out, 4096, 3072, 4096, 0);
}

// Round 11
// 1090.803 us; speedup vs baseline: 1.0247x; 1.0247x over previous
//
#include <hip/hip_runtime.h>

typedef short bf16x8 __attribute__((ext_vector_type(8)));
typedef float f32x4 __attribute__((ext_vector_type(4)));

#define S_LEN 2048
#define NHQ 16
#define NKV 8
#define HD 256

__device__ __forceinline__ unsigned short f2bf(float f){
  unsigned u = __float_as_uint(f);
  unsigned r = (u + 0x7FFFu + ((u >> 16) & 1u)) >> 16;
  return (unsigned short)r;
}
__device__ __forceinline__ float bf2f(unsigned short h){
  return __uint_as_float(((unsigned)h) << 16);
}
__device__ __forceinline__ unsigned pack2(float a, float b){
  return (unsigned)f2bf(a) | ((unsigned)f2bf(b) << 16);
}

// async global->LDS, 16B per lane; LDS dest is wave-uniform base + lane*16 (HW-linear)
__device__ __forceinline__ void gload_lds16(const void* g, void* l){
  __builtin_amdgcn_global_load_lds(
      (const __attribute__((address_space(1))) void*)g,
      (__attribute__((address_space(3))) void*)l, 16, 0, 0);
}

// ---------------- elementwise f32 -> bf16 ----------------
__global__ void k_conv(const float* __restrict__ in, unsigned short* __restrict__ out, int n){
  int i = (blockIdx.x * 256 + threadIdx.x) * 4;
  if (i < n){
    float4 v = *(const float4*)&in[i];
    ushort4 o;
    o.x = f2bf(v.x); o.y = f2bf(v.y); o.z = f2bf(v.z); o.w = f2bf(v.w);
    *(ushort4*)&out[i] = o;
  }
}

// ---------------- tiled transpose + convert: in (R x C) f32 -> out (C x R) bf16 ----------------
__global__ void k_tconv(const float* __restrict__ in, unsigned short* __restrict__ out, int R, int C){
  __shared__ float tile[32][33];
  int c0 = blockIdx.x * 32, r0 = blockIdx.y * 32;
  int tx = threadIdx.x, ty = threadIdx.y;
  for (int i = 0; i < 4; i++)
    tile[ty + i*8][tx] = in[(size_t)(r0 + ty + i*8) * C + c0 + tx];
  __syncthreads();
  for (int i = 0; i < 4; i++)
    out[(size_t)(c0 + ty + i*8) * R + r0 + tx] = f2bf(tile[tx][ty + i*8]);
}

// ---------------- bf16 transpose for V: per (b,kv): (S x D) -> (D x S) ----------------
__global__ void k_vtrans(const unsigned short* __restrict__ V, unsigned short* __restrict__ VT){
  __shared__ unsigned short tile[32][40];
  int s0 = blockIdx.x * 32, d0 = blockIdx.y * 32, bz = blockIdx.z; // bz = b*NKV+kv
  int b = bz >> 3, kv = bz & 7;
  int tx = threadIdx.x, ty = threadIdx.y;
  for (int i = 0; i < 4; i++)
    tile[ty + i*8][tx] = V[(size_t)(b * S_LEN + s0 + ty + i*8) * (NKV*HD) + kv*HD + d0 + tx];
  __syncthreads();
  for (int i = 0; i < 4; i++)
    VT[((size_t)(bz * HD + d0 + ty + i*8)) * S_LEN + s0 + tx] = tile[tx][ty + i*8];
}

// ---------------- in-place RoPE on bf16 buffer (token, nh, 256), vectorized x8 ----------------
__global__ void k_rope(unsigned short* buf, const float* __restrict__ cosb,
                       const float* __restrict__ sinb, int lgnh){
  int idx = blockIdx.x * 256 + threadIdx.x;
  int d0 = (idx & 15) * 8;
  int h = (idx >> 4) & ((1 << lgnh) - 1);
  int t = idx >> (4 + lgnh);
  float ca[8], sa[8];
  *(float4*)&ca[0] = *(const float4*)&cosb[t * 128 + d0];
  *(float4*)&ca[4] = *(const float4*)&cosb[t * 128 + d0 + 4];
  *(float4*)&sa[0] = *(const float4*)&sinb[t * 128 + d0];
  *(float4*)&sa[4] = *(const float4*)&sinb[t * 128 + d0 + 4];
  size_t base = ((size_t)t << (lgnh + 8)) + ((size_t)h << 8) + d0;
  bf16x8 x1 = *(const bf16x8*)&buf[base];
  bf16x8 x2 = *(const bf16x8*)&buf[base + 128];
  bf16x8 o1, o2;
  #pragma unroll
  for (int j = 0; j < 8; j++){
    float f1 = bf2f((unsigned short)x1[j]), f2 = bf2f((unsigned short)x2[j]);
    o1[j] = (short)f2bf(f1 * ca[j] - f2 * sa[j]);
    o2[j] = (short)f2bf(f1 * sa[j] + f2 * ca[j]);
  }
  *(bf16x8*)&buf[base] = o1;
  *(bf16x8*)&buf[base + 128] = o2;
}

// ---------------- bf16 GEMM: C(MxN) = A(MxK) @ Bt(NxK)^T ; out f32 or bf16 ----------------
// staging via global_load_lds width=16 with linear LDS dest + inverse-XOR-swizzled global
// source; XCD-bijective block swizzle (T1).
__global__ __launch_bounds__(256) void k_gemm_bt(const unsigned short* __restrict__ A,
    const unsigned short* __restrict__ Bt, void* __restrict__ Cp,
    int M, int N, int K, int out_bf16){
  __shared__ __align__(16) unsigned short smem[2 * 128 * 64];  // 32 KB: As|Bs, reused as C-stage
  unsigned short* As = smem;
  unsigned short* Bs = smem + 128 * 64;
  int tid = threadIdx.x;
  int lane = tid & 63, wave = tid >> 6, quad = lane >> 4, l16 = lane & 15;
  int wm = wave >> 1, wn = wave & 1;
  // XCD-bijective swizzle: all launches have nwg % 8 == 0
  int nx = gridDim.x;
  int flat = blockIdx.y * nx + blockIdx.x;
  int cpx = (nx * gridDim.y) >> 3;
  int swz = (flat & 7) * cpx + (flat >> 3);
  int bm0 = (swz / nx) * 128, bn0 = (swz % nx) * 128;
  const unsigned short* Ag = &A[(size_t)bm0 * K];
  const unsigned short* Bg = &Bt[(size_t)bn0 * K];
  int srow = lane >> 3;                 // row-in-window
  int spc  = lane & 7;                  // LDS chunk index (linear dest)
  f32x4 acc[4][4] = {};
  for (int k0 = 0; k0 < K; k0 += 64){
    __syncthreads();
    // async staging: 16 windows x 1KB per matrix; window = it*4 + wave (wave-uniform dest)
    for (int it = 0; it < 4; it++){
      int win = it * 4 + wave;
      int row = win * 8 + srow;
      int c   = spc ^ (row & 7);        // inverse swizzle on SOURCE; LDS stays linear
      gload_lds16(&Ag[(size_t)row * K + k0 + c * 8], &As[win * 512]);
      gload_lds16(&Bg[(size_t)row * K + k0 + c * 8], &Bs[win * 512]);
    }
    __syncthreads();                    // compiler drains vmcnt(0) before barrier
    for (int ks = 0; ks < 2; ks++){
      bf16x8 af[4], bfr[4];
      for (int mt = 0; mt < 4; mt++){
        int row = wm * 64 + mt * 16 + l16;
        int pc = (ks * 4 + quad) ^ (row & 7);
        af[mt] = *(const bf16x8*)&As[row * 64 + pc * 8];
      }
      for (int nt = 0; nt < 4; nt++){
        int row = wn * 64 + nt * 16 + l16;
        int pc = (ks * 4 + quad) ^ (row & 7);
        bfr[nt] = *(const bf16x8*)&Bs[row * 64 + pc * 8];
      }
      for (int mt = 0; mt < 4; mt++)
        for (int nt = 0; nt < 4; nt++)
          acc[mt][nt] = __builtin_amdgcn_mfma_f32_16x16x32_bf16(af[mt], bfr[nt], acc[mt][nt], 0, 0, 0);
    }
  }
  // ---- coalesced epilogue: stage 64 rows of C at a time in LDS, store 16B/lane ----
  float* Ct = (float*)smem;  // 64 x 128 f32 = 32 KB
  for (int p = 0; p < 2; p++){
    __syncthreads();
    if (wm == p){
      for (int mt = 0; mt < 4; mt++)
        for (int nt = 0; nt < 4; nt++)
          for (int r = 0; r < 4; r++)
            Ct[(mt * 16 + quad * 4 + r) * 128 + wn * 64 + nt * 16 + l16] = acc[mt][nt][r];
    }
    __syncthreads();
    if (out_bf16){
      unsigned short* O = (unsigned short*)Cp;
      for (int j = 0; j < 4; j++){
        int chunk = j * 256 + tid;        // 1024 chunks x 8 elems
        int row = chunk >> 4, col = (chunk & 15) * 8;
        const float* src = &Ct[row * 128 + col];
        uint4 o;
        o.x = pack2(src[0], src[1]);
        o.y = pack2(src[2], src[3]);
        o.z = pack2(src[4], src[5]);
        o.w = pack2(src[6], src[7]);
        *(uint4*)&O[(size_t)(bm0 + p * 64 + row) * N + bn0 + col] = o;
      }
    } else {
      float* O = (float*)Cp;
      for (int j = 0; j < 8; j++){
        int chunk = j * 256 + tid;        // 2048 chunks x 4 elems
        int row = chunk >> 5, col = (chunk & 31) * 4;
        *(float4*)&O[(size_t)(bm0 + p * 64 + row) * N + bn0 + col] = *(const float4*)&Ct[row * 128 + col];
      }
    }
  }
}

// ---------------- flash attention (v10r: retry — v4 dbuf schedule + swizzled LDS + 512-blk) --
// Q (token, 16, 256) bf16 roped; K (token, 8, 256) bf16 roped; VT (b,kv,256,S) bf16.
// Out (token, 16*256) bf16.
// grid (x=bkv=16, y=32) = 512 blocks, 512 thr = 8 waves: wave = rowgrp(4) x head(2).
// qt = y<16 ? y : 47-y -> blocks c and c+256 carry qt and 31-qt; with 2 blocks/CU all 512
// are resident from t=0 and each CU totals exactly 66 k-tiles (balanced).
// linear id = y*16+bkv -> id%8 == bkv%8: XCD-local K/VT (v4-verified FETCH 265->33 MB).
// v4-proven schedule: dbuf, reg-prefetch of tile kt+1, ONE barrier per k-tile.
// v7/v9-proven conflict-free LDS (2.67e7 -> ~1e6): Ks stride 256 + 16B-chunk XOR
// involution (write (c^kr), read ((ks*4+quad)^row)); VTs stride 36 shorts.
// LDS = 79872 B -> 2 blocks/CU feasible (159744 <= 163840); VGPR ~112 at (512,2), no spill.
__global__ __launch_bounds__(512, 2) void k_flash(const unsigned short* __restrict__ Q,
    const unsigned short* __restrict__ Kg, const unsigned short* __restrict__ VTg,
    unsigned short* __restrict__ Og){
  // [buf0: Ks 32x256 swz (8192) | VTs 256x36 (9216)][buf1: same][Ps 8x16x40 (5120)]
  __shared__ __align__(16) unsigned short smem[2 * 17408 + 8 * 16 * 40];
  const int BUFSZ = 17408;
  int tid = threadIdx.x;
  int lane = tid & 63, wave = tid >> 6, quad = lane >> 4, l16 = lane & 15;
  int hig = wave & 1, rowgrp = wave >> 1;        // 2 heads share this block's K/V staging
  int bkv = blockIdx.x, y = blockIdx.y;
  int qt = (y < 16) ? y : 47 - y;
  int b = bkv >> 3, kv = bkv & 7;
  int h = kv * 2 + hig;
  const float L2E = 1.4426950408889634f;
  const float scale = 0.0625f; // 1/sqrt(256)

  size_t kgbase = (size_t)(b * S_LEN) * (NKV*HD) + (size_t)kv * HD;
  size_t vtbase = ((size_t)(b * NKV + kv) * HD) * S_LEN;
  unsigned short* Ps = smem + 2 * BUFSZ + wave * (16 * 40);

  int qmin = qt * 64 + rowgrp * 16;
  int nkt = qt * 2 + 2;

  // Q fragments in registers: this wave's 16 q-rows for head h
  bf16x8 qf[8];
  {
    size_t qoff = ((size_t)(b * S_LEN + qt * 64 + rowgrp * 16 + l16)) * (NHQ * HD) + (size_t)h * HD;
    for (int ks = 0; ks < 8; ks++)
      qf[ks] = *(const bf16x8*)&Q[qoff + ks * 32 + quad * 8];
  }
  f32x4 acc[16] = {};
  float mrow[4], lrow[4];
  for (int r = 0; r < 4; r++){ mrow[r] = -1e30f; lrow[r] = 0.f; }

  // prologue: prefetch tile 0 into registers
  uint4 stk[2], stv[2];
  for (int it = 0; it < 2; it++){
    int slot = it * 512 + tid;
    int kr = slot >> 5, c = slot & 31;
    stk[it] = *(const uint4*)&Kg[kgbase + (size_t)kr * (NKV*HD) + c * 8];
    int dd = slot >> 2, c2 = slot & 3;
    stv[it] = *(const uint4*)&VTg[vtbase + (size_t)dd * S_LEN + c2 * 8];
  }

  for (int kt = 0; kt < nkt; kt++){
    unsigned short* Ks  = smem + (kt & 1) * BUFSZ;
    unsigned short* VTs = Ks + 8192;
    // write staged regs (tile kt) -> LDS buf[kt&1], swizzled
    for (int it = 0; it < 2; it++){
      int slot = it * 512 + tid;
      int kr = slot >> 5, c = slot & 31;
      *(uint4*)&Ks[kr * 256 + (c ^ kr) * 8] = stk[it];
      int dd = slot >> 2, c2 = slot & 3;
      *(uint4*)&VTs[dd * 36 + c2 * 8] = stv[it];
    }
    // prefetch tile kt+1 -> registers (latency hides under barrier+compute)
    if (kt + 1 < nkt){
      for (int it = 0; it < 2; it++){
        int slot = it * 512 + tid;
        int kr = slot >> 5, c = slot & 31;
        stk[it] = *(const uint4*)&Kg[kgbase + (size_t)((kt + 1) * 32 + kr) * (NKV*HD) + c * 8];
        int dd = slot >> 2, c2 = slot & 3;
        stv[it] = *(const uint4*)&VTg[vtbase + (size_t)dd * S_LEN + (kt + 1) * 32 + c2 * 8];
      }
    }
    __syncthreads();
    if (kt * 32 > qmin + 15) continue;  // wave-uniform: tile fully above causal diag

    // S = Q @ K^T  (16 x 32 per wave)
    f32x4 sv[2] = {};
    __builtin_amdgcn_s_setprio(1);
    for (int ks = 0; ks < 8; ks++){
      for (int nt = 0; nt < 2; nt++){
        int row = nt * 16 + l16;
        bf16x8 kf = *(const bf16x8*)&Ks[row * 256 + ((ks * 4 + quad) ^ row) * 8];
        sv[nt] = __builtin_amdgcn_mfma_f32_16x16x32_bf16(qf[ks], kf, sv[nt], 0, 0, 0);
      }
    }
    __builtin_amdgcn_s_setprio(0);
    // scale + causal mask + row max (rows = quad*4+r, cols = kt*32 + nt*16 + l16)
    float pv[2][4], tmax[4];
    for (int r = 0; r < 4; r++){
      int qr = qmin + quad * 4 + r;
      float mx = -1e30f;
      for (int nt = 0; nt < 2; nt++){
        int key = kt * 32 + nt * 16 + l16;
        float v = sv[nt][r] * scale;
        if (key > qr) v = -1e30f;
        pv[nt][r] = v;
        mx = fmaxf(mx, v);
      }
      tmax[r] = mx;
    }
    for (int off = 1; off < 16; off <<= 1)
      for (int r = 0; r < 4; r++)
        tmax[r] = fmaxf(tmax[r], __shfl_xor(tmax[r], off, 64));
    // defer-max THR=0: skip rescale when no row max grew (skipped work is exactly *1.0)
    int grow = (tmax[0] > mrow[0]) | (tmax[1] > mrow[1]) |
               (tmax[2] > mrow[2]) | (tmax[3] > mrow[3]);
    if (grow){
      float alpha[4];
      for (int r = 0; r < 4; r++){
        float mn = fmaxf(mrow[r], tmax[r]);
        alpha[r] = exp2f((mrow[r] - mn) * L2E);
        mrow[r] = mn;
        lrow[r] *= alpha[r];
      }
      for (int i = 0; i < 16; i++)
        for (int r = 0; r < 4; r++) acc[i][r] *= alpha[r];
    }
    float pb[2][4], psum[4] = {0.f, 0.f, 0.f, 0.f};
    for (int nt = 0; nt < 2; nt++)
      for (int r = 0; r < 4; r++){
        float pe = exp2f((pv[nt][r] - mrow[r]) * L2E);
        pb[nt][r] = pe; psum[r] += pe;
      }
    for (int off = 1; off < 16; off <<= 1)
      for (int r = 0; r < 4; r++)
        psum[r] += __shfl_xor(psum[r], off, 64);
    for (int r = 0; r < 4; r++) lrow[r] += psum[r];
    // P: C-layout -> LDS -> A-layout (per-wave private, no barrier needed)
    for (int nt = 0; nt < 2; nt++)
      for (int r = 0; r < 4; r++)
        Ps[(quad * 4 + r) * 40 + nt * 16 + l16] = f2bf(pb[nt][r]);
    bf16x8 pa = *(const bf16x8*)&Ps[l16 * 40 + quad * 8];
    // O += P @ V   (16 x 256 per wave)
    __builtin_amdgcn_s_setprio(1);
    for (int nt = 0; nt < 16; nt++){
      bf16x8 vf = *(const bf16x8*)&VTs[(nt * 16 + l16) * 36 + quad * 8];
      acc[nt] = __builtin_amdgcn_mfma_f32_16x16x32_bf16(pa, vf, acc[nt], 0, 0, 0);
    }
    __builtin_amdgcn_s_setprio(0);
  }
  // ---- coalesced epilogue: per-wave O tile (16 x 256 bf16) via LDS, 16B/lane stores ----
  float inv[4];
  for (int r = 0; r < 4; r++) inv[r] = 1.0f / lrow[r];
  __syncthreads();  // all waves done with Ks/VTs before overwriting with Ot
  unsigned short* Ot = smem + wave * (16 * 256);  // 8 KB per wave (fits in dbuf region)
  for (int nt = 0; nt < 16; nt++)
    for (int r = 0; r < 4; r++)
      Ot[(quad * 4 + r) * 256 + nt * 16 + l16] = f2bf(acc[nt][r] * inv[r]);
  size_t obase = ((size_t)(b * S_LEN + qt * 64 + rowgrp * 16)) * (NHQ * HD) + (size_t)h * HD;
  for (int j = 0; j < 8; j++){
    int chunk = j * 64 + lane;      // 512 chunks x 8 shorts
    int row = chunk >> 5, col = (chunk & 31) * 8;
    *(uint4*)&Og[obase + (size_t)row * (NHQ * HD) + col] = *(const uint4*)&Ot[row * 256 + col];
  }
}

extern "C" void kernel_launch(void* const* d_in, const int* in_sizes, int n_in,
                              void* d_out, int out_size, void* d_ws, size_t ws_size,
                              hipStream_t stream){
  const float* hid  = (const float*)d_in[0];
  const float* cosb = (const float*)d_in[1];
  const float* sinb = (const float*)d_in[2];
  // d_in[3] = mask (causal, reconstructed analytically)
  const float* wq = (const float*)d_in[4];
  const float* wk = (const float*)d_in[5];
  const float* wv = (const float*)d_in[6];
  const float* wo = (const float*)d_in[7];

  char* ws = (char*)d_ws;
  size_t off = 0;
  auto alloc = [&](size_t bytes) -> void* {
    void* p = ws + off; off += (bytes + 255) & ~(size_t)255; return p;
  };
  unsigned short* Xbf = (unsigned short*)alloc(4096ull * 3072 * 2);
  unsigned short* WqT = (unsigned short*)alloc(4096ull * 3072 * 2);
  unsigned short* WkT = (unsigned short*)alloc(2048ull * 3072 * 2);
  unsigned short* WvT = (unsigned short*)alloc(2048ull * 3072 * 2);
  unsigned short* WoT = (unsigned short*)alloc(3072ull * 4096 * 2);
  unsigned short* Qb  = (unsigned short*)alloc(4096ull * 4096 * 2);
  unsigned short* Kb  = (unsigned short*)alloc(4096ull * 2048 * 2);
  unsigned short* Vb  = (unsigned short*)alloc(4096ull * 2048 * 2);
  unsigned short* VTb = (unsigned short*)alloc(4096ull * 2048 * 2);
  unsigned short* Ab  = (unsigned short*)alloc(4096ull * 4096 * 2);

  k_conv<<<12288, 256, 0, stream>>>(hid, Xbf, 4096 * 3072);
  k_tconv<<<dim3(128, 96), dim3(32, 8), 0, stream>>>(wq, WqT, 3072, 4096);
  k_tconv<<<dim3(64, 96),  dim3(32, 8), 0, stream>>>(wk, WkT, 3072, 2048);
  k_tconv<<<dim3(64, 96),  dim3(32, 8), 0, stream>>>(wv, WvT, 3072, 2048);
  k_tconv<<<dim3(96, 128), dim3(32, 8), 0, stream>>>(wo, WoT, 4096, 3072);
  k_gemm_bt<<<dim3(32, 32), 256, 0, stream>>>(Xbf, WqT, Qb, 4096, 4096, 3072, 1);
  k_gemm_bt<<<dim3(16, 32), 256, 0, stream>>>(Xbf, WkT, Kb, 4096, 2048, 3072, 1);
  k_gemm_bt<<<dim3(16, 32), 256, 0, stream>>>(Xbf, WvT, Vb, 4096, 2048, 3072, 1);
  k_rope<<<4096, 256, 0, stream>>>(Qb, cosb, sinb, 4);
  k_rope<<<2048, 256, 0, stream>>>(Kb, cosb, sinb, 3);
  k_vtrans<<<dim3(64, 8, 16), dim3(32, 8), 0, stream>>>(Vb, VTb);
  k_flash<<<dim3(16, 32), 512, 0, stream>>>(Qb, Kb, VTb, Ab);
  k_gemm_bt<<<dim3(24, 32), 256, 0, stream>>>(Ab, WoT, d_out, 4096, 3072, 4096, 0);
}

// Round 12
// 881.008 us; speedup vs baseline: 1.2687x; 1.2381x over previous
//
#include <hip/hip_runtime.h>

typedef short bf16x8 __attribute__((ext_vector_type(8)));
typedef float f32x4 __attribute__((ext_vector_type(4)));

#define S_LEN 2048
#define NHQ 16
#define NKV 8
#define HD 256

__device__ __forceinline__ unsigned short f2bf(float f){
  unsigned u = __float_as_uint(f);
  unsigned r = (u + 0x7FFFu + ((u >> 16) & 1u)) >> 16;
  return (unsigned short)r;
}
__device__ __forceinline__ float bf2f(unsigned short h){
  return __uint_as_float(((unsigned)h) << 16);
}
__device__ __forceinline__ unsigned pack2(float a, float b){
  return (unsigned)f2bf(a) | ((unsigned)f2bf(b) << 16);
}

// async global->LDS, 16B per lane; LDS dest is wave-uniform base + lane*16 (HW-linear)
__device__ __forceinline__ void gload_lds16(const void* g, void* l){
  __builtin_amdgcn_global_load_lds(
      (const __attribute__((address_space(1))) void*)g,
      (__attribute__((address_space(3))) void*)l, 16, 0, 0);
}

// ---------------- elementwise f32 -> bf16 ----------------
__global__ void k_conv(const float* __restrict__ in, unsigned short* __restrict__ out, int n){
  int i = (blockIdx.x * 256 + threadIdx.x) * 4;
  if (i < n){
    float4 v = *(const float4*)&in[i];
    ushort4 o;
    o.x = f2bf(v.x); o.y = f2bf(v.y); o.z = f2bf(v.z); o.w = f2bf(v.w);
    *(ushort4*)&out[i] = o;
  }
}

// ---------------- tiled transpose + convert: in (R x C) f32 -> out (C x R) bf16 ----------------
// store phase widened to ushort4 (8 B/lane): thread tid -> oc = tid>>3 (out row, c-dim),
// og = tid&7 (4 consecutive out cols, r-dim). LDS reads tile[og*4+j][oc]: bank =
// (4*og + j + oc) mod 32 -> 2 lanes/bank per wave (free, m136).
__global__ void k_tconv(const float* __restrict__ in, unsigned short* __restrict__ out, int R, int C){
  __shared__ float tile[32][33];
  int c0 = blockIdx.x * 32, r0 = blockIdx.y * 32;
  int tx = threadIdx.x, ty = threadIdx.y;
  for (int i = 0; i < 4; i++)
    tile[ty + i*8][tx] = in[(size_t)(r0 + ty + i*8) * C + c0 + tx];
  __syncthreads();
  int tid = ty * 32 + tx;
  int oc = tid >> 3, og = tid & 7;
  ushort4 u;
  u.x = f2bf(tile[og*4 + 0][oc]);
  u.y = f2bf(tile[og*4 + 1][oc]);
  u.z = f2bf(tile[og*4 + 2][oc]);
  u.w = f2bf(tile[og*4 + 3][oc]);
  *(ushort4*)&out[(size_t)(c0 + oc) * R + r0 + og*4] = u;
}

// ---------------- bf16 transpose for V: per (b,kv): (S x D) -> (D x S) ----------------
// store phase widened to ushort4 (8 B/lane), same mapping as k_tconv.
__global__ void k_vtrans(const unsigned short* __restrict__ V, unsigned short* __restrict__ VT){
  __shared__ unsigned short tile[32][40];
  int s0 = blockIdx.x * 32, d0 = blockIdx.y * 32, bz = blockIdx.z; // bz = b*NKV+kv
  int b = bz >> 3, kv = bz & 7;
  int tx = threadIdx.x, ty = threadIdx.y;
  for (int i = 0; i < 4; i++)
    tile[ty + i*8][tx] = V[(size_t)(b * S_LEN + s0 + ty + i*8) * (NKV*HD) + kv*HD + d0 + tx];
  __syncthreads();
  int tid = ty * 32 + tx;
  int oc = tid >> 3, og = tid & 7;   // oc = d index, og*4.. = s offsets
  ushort4 u;
  u.x = tile[og*4 + 0][oc];
  u.y = tile[og*4 + 1][oc];
  u.z = tile[og*4 + 2][oc];
  u.w = tile[og*4 + 3][oc];
  *(ushort4*)&VT[((size_t)(bz * HD + d0 + oc)) * S_LEN + s0 + og*4] = u;
}

// ---------------- in-place RoPE on bf16 buffer (token, nh, 256), vectorized x8 ----------------
__global__ void k_rope(unsigned short* buf, const float* __restrict__ cosb,
                       const float* __restrict__ sinb, int lgnh){
  int idx = blockIdx.x * 256 + threadIdx.x;
  int d0 = (idx & 15) * 8;
  int h = (idx >> 4) & ((1 << lgnh) - 1);
  int t = idx >> (4 + lgnh);
  float ca[8], sa[8];
  *(float4*)&ca[0] = *(const float4*)&cosb[t * 128 + d0];
  *(float4*)&ca[4] = *(const float4*)&cosb[t * 128 + d0 + 4];
  *(float4*)&sa[0] = *(const float4*)&sinb[t * 128 + d0];
  *(float4*)&sa[4] = *(const float4*)&sinb[t * 128 + d0 + 4];
  size_t base = ((size_t)t << (lgnh + 8)) + ((size_t)h << 8) + d0;
  bf16x8 x1 = *(const bf16x8*)&buf[base];
  bf16x8 x2 = *(const bf16x8*)&buf[base + 128];
  bf16x8 o1, o2;
  #pragma unroll
  for (int j = 0; j < 8; j++){
    float f1 = bf2f((unsigned short)x1[j]), f2 = bf2f((unsigned short)x2[j]);
    o1[j] = (short)f2bf(f1 * ca[j] - f2 * sa[j]);
    o2[j] = (short)f2bf(f1 * sa[j] + f2 * ca[j]);
  }
  *(bf16x8*)&buf[base] = o1;
  *(bf16x8*)&buf[base + 128] = o2;
}

// ---------------- bf16 GEMM: C(MxN) = A(MxK) @ Bt(NxK)^T ; out f32 or bf16 ----------------
// staging via global_load_lds width=16 with linear LDS dest + inverse-XOR-swizzled global
// source; XCD-bijective block swizzle (T1).
__global__ __launch_bounds__(256) void k_gemm_bt(const unsigned short* __restrict__ A,
    const unsigned short* __restrict__ Bt, void* __restrict__ Cp,
    int M, int N, int K, int out_bf16){
  __shared__ __align__(16) unsigned short smem[2 * 128 * 64];  // 32 KB: As|Bs, reused as C-stage
  unsigned short* As = smem;
  unsigned short* Bs = smem + 128 * 64;
  int tid = threadIdx.x;
  int lane = tid & 63, wave = tid >> 6, quad = lane >> 4, l16 = lane & 15;
  int wm = wave >> 1, wn = wave & 1;
  // XCD-bijective swizzle: all launches have nwg % 8 == 0
  int nx = gridDim.x;
  int flat = blockIdx.y * nx + blockIdx.x;
  int cpx = (nx * gridDim.y) >> 3;
  int swz = (flat & 7) * cpx + (flat >> 3);
  int bm0 = (swz / nx) * 128, bn0 = (swz % nx) * 128;
  const unsigned short* Ag = &A[(size_t)bm0 * K];
  const unsigned short* Bg = &Bt[(size_t)bn0 * K];
  int srow = lane >> 3;                 // row-in-window
  int spc  = lane & 7;                  // LDS chunk index (linear dest)
  f32x4 acc[4][4] = {};
  for (int k0 = 0; k0 < K; k0 += 64){
    __syncthreads();
    // async staging: 16 windows x 1KB per matrix; window = it*4 + wave (wave-uniform dest)
    for (int it = 0; it < 4; it++){
      int win = it * 4 + wave;
      int row = win * 8 + srow;
      int c   = spc ^ (row & 7);        // inverse swizzle on SOURCE; LDS stays linear
      gload_lds16(&Ag[(size_t)row * K + k0 + c * 8], &As[win * 512]);
      gload_lds16(&Bg[(size_t)row * K + k0 + c * 8], &Bs[win * 512]);
    }
    __syncthreads();                    // compiler drains vmcnt(0) before barrier
    for (int ks = 0; ks < 2; ks++){
      bf16x8 af[4], bfr[4];
      for (int mt = 0; mt < 4; mt++){
        int row = wm * 64 + mt * 16 + l16;
        int pc = (ks * 4 + quad) ^ (row & 7);
        af[mt] = *(const bf16x8*)&As[row * 64 + pc * 8];
      }
      for (int nt = 0; nt < 4; nt++){
        int row = wn * 64 + nt * 16 + l16;
        int pc = (ks * 4 + quad) ^ (row & 7);
        bfr[nt] = *(const bf16x8*)&Bs[row * 64 + pc * 8];
      }
      for (int mt = 0; mt < 4; mt++)
        for (int nt = 0; nt < 4; nt++)
          acc[mt][nt] = __builtin_amdgcn_mfma_f32_16x16x32_bf16(af[mt], bfr[nt], acc[mt][nt], 0, 0, 0);
    }
  }
  // ---- coalesced epilogue: stage 64 rows of C at a time in LDS, store 16B/lane ----
  float* Ct = (float*)smem;  // 64 x 128 f32 = 32 KB
  for (int p = 0; p < 2; p++){
    __syncthreads();
    if (wm == p){
      for (int mt = 0; mt < 4; mt++)
        for (int nt = 0; nt < 4; nt++)
          for (int r = 0; r < 4; r++)
            Ct[(mt * 16 + quad * 4 + r) * 128 + wn * 64 + nt * 16 + l16] = acc[mt][nt][r];
    }
    __syncthreads();
    if (out_bf16){
      unsigned short* O = (unsigned short*)Cp;
      for (int j = 0; j < 4; j++){
        int chunk = j * 256 + tid;        // 1024 chunks x 8 elems
        int row = chunk >> 4, col = (chunk & 15) * 8;
        const float* src = &Ct[row * 128 + col];
        uint4 o;
        o.x = pack2(src[0], src[1]);
        o.y = pack2(src[2], src[3]);
        o.z = pack2(src[4], src[5]);
        o.w = pack2(src[6], src[7]);
        *(uint4*)&O[(size_t)(bm0 + p * 64 + row) * N + bn0 + col] = o;
      }
    } else {
      float* O = (float*)Cp;
      for (int j = 0; j < 8; j++){
        int chunk = j * 256 + tid;        // 2048 chunks x 4 elems
        int row = chunk >> 5, col = (chunk & 31) * 4;
        *(float4*)&O[(size_t)(bm0 + p * 64 + row) * N + bn0 + col] = *(const float4*)&Ct[row * 128 + col];
      }
    }
  }
}

// ---------------- flash attention (v4-exact: the verified 232 us local optimum) -------------
// Q (token, 16, 256) bf16 roped; K (token, 8, 256) bf16 roped; VT (b,kv,256,S) bf16
// Out (token, 16*256) bf16.
// grid (x=bkv=16, y=p=16), block 512 = 8 waves: wave = rowgrp(4) x head-in-group(2).
// linear block id = p*16 + bkv -> id%8 == bkv%8: XCD-local K/VT (verified FETCH 265->33 MB).
// Block p processes q-tiles {p, 31-p}: exactly 66 k-tiles per block (0 tail).
// dbuf + reg-prefetch of tile kt+1, ONE barrier per k-tile. VGPR 104, no spill.
// NOTE: six structural variants (single-buf T14, 256-thr, packed-QKV, Ks-XOR swizzle,
// 512-blk 2/CU) all regressed: swizzle triggers regalloc spill (WRITE 116-272 MB);
// 2 blocks/CU never materializes at ~80 KB LDS. This config is the measured optimum.
__global__ __launch_bounds__(512, 2) void k_flash(const unsigned short* __restrict__ Q,
    const unsigned short* __restrict__ Kg, const unsigned short* __restrict__ VTg,
    unsigned short* __restrict__ Og){
  // [buf0: Ks 32x264 | VTs 256x40][buf1: same][Ps 8 waves x 16x40]
  __shared__ __align__(16) unsigned short smem[2 * (32*264 + 256*40) + 8 * 16 * 40];
  const int BUFSZ = 32*264 + 256*40;  // 18688 shorts per buffer
  int tid = threadIdx.x;
  int lane = tid & 63, wave = tid >> 6, quad = lane >> 4, l16 = lane & 15;
  int hig = wave & 1, rowgrp = wave >> 1;        // 2 heads share this block's K/V staging
  int bkv = blockIdx.x, p = blockIdx.y;
  int b = bkv >> 3, kv = bkv & 7;
  int h = kv * 2 + hig;
  const float L2E = 1.4426950408889634f;
  const float scale = 0.0625f; // 1/sqrt(256)

  size_t kgbase = (size_t)(b * S_LEN) * (NKV*HD) + (size_t)kv * HD;
  size_t vtbase = ((size_t)(b * NKV + kv) * HD) * S_LEN;
  unsigned short* Ps = smem + 2 * BUFSZ + wave * (16 * 40);

  for (int ph = 0; ph < 2; ph++){
    int qt = ph ? (31 - p) : p;
    int qmin = qt * 64 + rowgrp * 16;
    int nkt = qt * 2 + 2;

    // Q fragments in registers: this wave's 16 q-rows for head h
    bf16x8 qf[8];
    {
      size_t qoff = ((size_t)(b * S_LEN + qt * 64 + rowgrp * 16 + l16)) * (NHQ * HD) + (size_t)h * HD;
      for (int ks = 0; ks < 8; ks++)
        qf[ks] = *(const bf16x8*)&Q[qoff + ks * 32 + quad * 8];
    }
    f32x4 acc[16] = {};
    float mrow[4], lrow[4];
    for (int r = 0; r < 4; r++){ mrow[r] = -1e30f; lrow[r] = 0.f; }

    // prologue: prefetch tile 0 into registers
    uint4 stk[2], stv[2];
    for (int it = 0; it < 2; it++){
      int slot = it * 512 + tid;
      int kr = slot >> 5, c = slot & 31;
      stk[it] = *(const uint4*)&Kg[kgbase + (size_t)(kr) * (NKV*HD) + c * 8];
      int dd = slot >> 2, c2 = slot & 3;
      stv[it] = *(const uint4*)&VTg[vtbase + (size_t)dd * S_LEN + c2 * 8];
    }

    for (int kt = 0; kt < nkt; kt++){
      unsigned short* Ks  = smem + (kt & 1) * BUFSZ;
      unsigned short* VTs = Ks + 32 * 264;
      // write staged regs (tile kt) -> LDS buf[kt&1]
      for (int it = 0; it < 2; it++){
        int slot = it * 512 + tid;
        int kr = slot >> 5, c = slot & 31;
        *(uint4*)&Ks[kr * 264 + c * 8] = stk[it];
        int dd = slot >> 2, c2 = slot & 3;
        *(uint4*)&VTs[dd * 40 + c2 * 8] = stv[it];
      }
      // prefetch tile kt+1 -> registers (latency hides under barrier+compute)
      if (kt + 1 < nkt){
        for (int it = 0; it < 2; it++){
          int slot = it * 512 + tid;
          int kr = slot >> 5, c = slot & 31;
          stk[it] = *(const uint4*)&Kg[kgbase + (size_t)((kt + 1) * 32 + kr) * (NKV*HD) + c * 8];
          int dd = slot >> 2, c2 = slot & 3;
          stv[it] = *(const uint4*)&VTg[vtbase + (size_t)dd * S_LEN + (kt + 1) * 32 + c2 * 8];
        }
      }
      __syncthreads();
      if (kt * 32 > qmin + 15) continue;  // wave-uniform: tile fully above causal diag

      // S = Q @ K^T  (16 x 32 per wave)
      f32x4 sv[2] = {};
      __builtin_amdgcn_s_setprio(1);
      for (int ks = 0; ks < 8; ks++){
        for (int nt = 0; nt < 2; nt++){
          bf16x8 kf = *(const bf16x8*)&Ks[(nt * 16 + l16) * 264 + ks * 32 + quad * 8];
          sv[nt] = __builtin_amdgcn_mfma_f32_16x16x32_bf16(qf[ks], kf, sv[nt], 0, 0, 0);
        }
      }
      __builtin_amdgcn_s_setprio(0);
      // scale + causal mask + row max (rows = quad*4+r, cols = kt*32 + nt*16 + l16)
      float pv[2][4], tmax[4];
      for (int r = 0; r < 4; r++){
        int qr = qmin + quad * 4 + r;
        float mx = -1e30f;
        for (int nt = 0; nt < 2; nt++){
          int key = kt * 32 + nt * 16 + l16;
          float v = sv[nt][r] * scale;
          if (key > qr) v = -1e30f;
          pv[nt][r] = v;
          mx = fmaxf(mx, v);
        }
        tmax[r] = mx;
      }
      for (int off = 1; off < 16; off <<= 1)
        for (int r = 0; r < 4; r++)
          tmax[r] = fmaxf(tmax[r], __shfl_xor(tmax[r], off, 64));
      // defer-max THR=0: skip rescale when no row max grew (skipped work is exactly *1.0)
      int grow = (tmax[0] > mrow[0]) | (tmax[1] > mrow[1]) |
                 (tmax[2] > mrow[2]) | (tmax[3] > mrow[3]);
      if (grow){
        float alpha[4];
        for (int r = 0; r < 4; r++){
          float mn = fmaxf(mrow[r], tmax[r]);
          alpha[r] = exp2f((mrow[r] - mn) * L2E);
          mrow[r] = mn;
          lrow[r] *= alpha[r];
        }
        for (int i = 0; i < 16; i++)
          for (int r = 0; r < 4; r++) acc[i][r] *= alpha[r];
      }
      float pb[2][4], psum[4] = {0.f, 0.f, 0.f, 0.f};
      for (int nt = 0; nt < 2; nt++)
        for (int r = 0; r < 4; r++){
          float pe = exp2f((pv[nt][r] - mrow[r]) * L2E);
          pb[nt][r] = pe; psum[r] += pe;
        }
      for (int off = 1; off < 16; off <<= 1)
        for (int r = 0; r < 4; r++)
          psum[r] += __shfl_xor(psum[r], off, 64);
      for (int r = 0; r < 4; r++) lrow[r] += psum[r];
      // P: C-layout -> LDS -> A-layout (per-wave private, no barrier needed)
      for (int nt = 0; nt < 2; nt++)
        for (int r = 0; r < 4; r++)
          Ps[(quad * 4 + r) * 40 + nt * 16 + l16] = f2bf(pb[nt][r]);
      bf16x8 pa = *(const bf16x8*)&Ps[l16 * 40 + quad * 8];
      // O += P @ V   (16 x 256 per wave)
      __builtin_amdgcn_s_setprio(1);
      for (int nt = 0; nt < 16; nt++){
        bf16x8 vf = *(const bf16x8*)&VTs[(nt * 16 + l16) * 40 + quad * 8];
        acc[nt] = __builtin_amdgcn_mfma_f32_16x16x32_bf16(pa, vf, acc[nt], 0, 0, 0);
      }
      __builtin_amdgcn_s_setprio(0);
    }
    // ---- coalesced epilogue: per-wave O tile (16 x 256 bf16) via LDS, 16B/lane stores ----
    float inv[4];
    for (int r = 0; r < 4; r++) inv[r] = 1.0f / lrow[r];
    __syncthreads();  // all waves done with Ks/VTs
    unsigned short* Ot = smem + wave * (16 * 256);  // 8 KB per wave (fits in dbuf region)
    for (int nt = 0; nt < 16; nt++)
      for (int r = 0; r < 4; r++)
        Ot[(quad * 4 + r) * 256 + nt * 16 + l16] = f2bf(acc[nt][r] * inv[r]);
    size_t obase = ((size_t)(b * S_LEN + qt * 64 + rowgrp * 16)) * (NHQ * HD) + (size_t)h * HD;
    for (int j = 0; j < 8; j++){
      int chunk = j * 64 + lane;      // 512 chunks x 8 shorts
      int row = chunk >> 5, col = (chunk & 31) * 8;
      *(uint4*)&Og[obase + (size_t)row * (NHQ * HD) + col] = *(const uint4*)&Ot[row * 256 + col];
    }
    __syncthreads();  // epilogue reads done before next phase's staging overwrites
  }
}

extern "C" void kernel_launch(void* const* d_in, const int* in_sizes, int n_in,
                              void* d_out, int out_size, void* d_ws, size_t ws_size,
                              hipStream_t stream){
  const float* hid  = (const float*)d_in[0];
  const float* cosb = (const float*)d_in[1];
  const float* sinb = (const float*)d_in[2];
  // d_in[3] = mask (causal, reconstructed analytically)
  const float* wq = (const float*)d_in[4];
  const float* wk = (const float*)d_in[5];
  const float* wv = (const float*)d_in[6];
  const float* wo = (const float*)d_in[7];

  char* ws = (char*)d_ws;
  size_t off = 0;
  auto alloc = [&](size_t bytes) -> void* {
    void* p = ws + off; off += (bytes + 255) & ~(size_t)255; return p;
  };
  unsigned short* Xbf = (unsigned short*)alloc(4096ull * 3072 * 2);
  unsigned short* WqT = (unsigned short*)alloc(4096ull * 3072 * 2);
  unsigned short* WkT = (unsigned short*)alloc(2048ull * 3072 * 2);
  unsigned short* WvT = (unsigned short*)alloc(2048ull * 3072 * 2);
  unsigned short* WoT = (unsigned short*)alloc(3072ull * 4096 * 2);
  unsigned short* Qb  = (unsigned short*)alloc(4096ull * 4096 * 2);
  unsigned short* Kb  = (unsigned short*)alloc(4096ull * 2048 * 2);
  unsigned short* Vb  = (unsigned short*)alloc(4096ull * 2048 * 2);
  unsigned short* VTb = (unsigned short*)alloc(4096ull * 2048 * 2);
  unsigned short* Ab  = (unsigned short*)alloc(4096ull * 4096 * 2);

  k_conv<<<12288, 256, 0, stream>>>(hid, Xbf, 4096 * 3072);
  k_tconv<<<dim3(128, 96), dim3(32, 8), 0, stream>>>(wq, WqT, 3072, 4096);
  k_tconv<<<dim3(64, 96),  dim3(32, 8), 0, stream>>>(wk, WkT, 3072, 2048);
  k_tconv<<<dim3(64, 96),  dim3(32, 8), 0, stream>>>(wv, WvT, 3072, 2048);
  k_tconv<<<dim3(96, 128), dim3(32, 8), 0, stream>>>(wo, WoT, 4096, 3072);
  k_gemm_bt<<<dim3(32, 32), 256, 0, stream>>>(Xbf, WqT, Qb, 4096, 4096, 3072, 1);
  k_gemm_bt<<<dim3(16, 32), 256, 0, stream>>>(Xbf, WkT, Kb, 4096, 2048, 3072, 1);
  k_gemm_bt<<<dim3(16, 32), 256, 0, stream>>>(Xbf, WvT, Vb, 4096, 2048, 3072, 1);
  k_rope<<<4096, 256, 0, stream>>>(Qb, cosb, sinb, 4);
  k_rope<<<2048, 256, 0, stream>>>(Kb, cosb, sinb, 3);
  k_vtrans<<<dim3(64, 8, 16), dim3(32, 8), 0, stream>>>(Vb, VTb);
  k_flash<<<dim3(16, 16), 512, 0, stream>>>(Qb, Kb, VTb, Ab);
  k_gemm_bt<<<dim3(24, 32), 256, 0, stream>>>(Ab, WoT, d_out, 4096, 3072, 4096, 0);
}